// Round 9
// baseline (155.416 us; speedup 1.0000x reference)
//
#include <hip/hip_runtime.h>
#include <math.h>

#define BATCH 32
#define TLEN 8192
#define NCH 64           // chunks
#define CLEN 128         // steps per chunk
#define SUBL 8           // steps per sub-chunk
#define NSUB 16          // sub-chunks per chunk
#define NROWS (BATCH*TLEN)   // 262144 rows

typedef _Float16 h2 __attribute__((ext_vector_type(2)));
union HU { unsigned int u; h2 h; };
__device__ __forceinline__ h2 u2h(unsigned int x) { HU t; t.u = x; return t.h; }
__device__ __forceinline__ unsigned int pkh(float a, float b) {
    HU t; t.h = h2{(_Float16)a, (_Float16)b}; return t.u;
}

#if __has_builtin(__builtin_amdgcn_fdot2)
__device__ __forceinline__ float dot2f(h2 a, h2 b, float c) {
    return __builtin_amdgcn_fdot2(a, b, c, false);
}
#else
__device__ __forceinline__ float dot2f(h2 a, h2 b, float c) {
    return fmaf((float)a.x, (float)b.x, fmaf((float)a.y, (float)b.y, c));
}
#endif

// ---------------------------------------------------------------------------
// HiPPO step, tree-form prefix: s <- (I - A/t) s + (x/t) * r
// ---------------------------------------------------------------------------
__device__ __forceinline__ void hippo_step(float s[8], float inv_t, float xb) {
    const float R[8] = {1.0f, 1.7320508075688772f, 2.23606797749979f,
                        2.6457513110645907f, 3.0f, 3.3166247903554f,
                        3.605551275463989f, 3.872983346207417f};
    float q0 = R[0]*s[0], q1 = R[1]*s[1], q2 = R[2]*s[2], q3 = R[3]*s[3];
    float q4 = R[4]*s[4], q5 = R[5]*s[5], q6 = R[6]*s[6];
    float t01 = q0+q1, t23 = q2+q3, t45 = q4+q5;
    float p1 = q0, p2 = t01, p3 = t01+q2, p4 = t01+t23;
    float p5 = p4+q4, p6 = p4+t45, p7 = p6+q6;
    float p[8] = {0.0f, p1, p2, p3, p4, p5, p6, p7};
    #pragma unroll
    for (int n = 0; n < 8; n++) {
        float as = fmaf(R[n], p[n], (float)(n + 1) * s[n]);
        s[n] = fmaf(-inv_t, as, fmaf(xb, R[n], s[n]));
    }
}

// ---------------------------------------------------------------------------
// Kernel A: per-chunk runs with 8-wide batched + double-buffered x loads.
// ---------------------------------------------------------------------------
__global__ void hippo_chunk_kernel(const float* __restrict__ x_seq,
                                   float* __restrict__ Psub,  // [NCH][NSUB][8][8]
                                   float* __restrict__ Vsub,  // [NCH][NSUB][64][8]
                                   float* __restrict__ Pfin,  // [NCH][8][8]
                                   float* __restrict__ Vfin)  // [NCH][64][8]
{
    int chunk = blockIdx.x;
    int tid = threadIdx.x;
    if (tid >= 72) return;
    bool isP = tid >= 64;
    int col = tid - 64;
    int b = tid >> 1, c = tid & 1;

    float s[8];
    #pragma unroll
    for (int n = 0; n < 8; n++) s[n] = (isP && n == col) ? 1.0f : 0.0f;

    int t0c = chunk * CLEN;
    size_t xbase = ((size_t)b * TLEN + t0c) * 2 + c;

    float xl[8];
    #pragma unroll
    for (int k = 0; k < 8; k++)
        xl[k] = isP ? 0.0f : x_seq[xbase + 2 * k];

    #pragma unroll 1
    for (int ii = 0; ii < CLEN; ii += 8) {
        int sub = ii >> 3;
        if (isP) {
            #pragma unroll
            for (int n = 0; n < 8; n++)
                Psub[(((size_t)chunk * NSUB + sub) * 8 + n) * 8 + col] = s[n];
        } else {
            #pragma unroll
            for (int n = 0; n < 8; n++)
                Vsub[(((size_t)chunk * NSUB + sub) * 64 + tid) * 8 + n] = s[n];
        }
        // prefetch next 8 inputs while computing current 8 steps
        float xn8[8];
        bool more = (ii + 8 < CLEN) && !isP;
        #pragma unroll
        for (int k = 0; k < 8; k++)
            xn8[k] = more ? x_seq[xbase + 2 * (ii + 8 + k)] : 0.0f;

        #pragma unroll
        for (int k = 0; k < 8; k++) {
            float tf = (float)(t0c + ii + k + 1);
            float inv_t = 1.0f / tf;
            hippo_step(s, inv_t, xl[k] * inv_t);
        }
        #pragma unroll
        for (int k = 0; k < 8; k++) xl[k] = xn8[k];
    }
    if (isP) {
        #pragma unroll
        for (int n = 0; n < 8; n++) Pfin[((size_t)chunk * 8 + n) * 8 + col] = s[n];
    } else {
        #pragma unroll
        for (int n = 0; n < 8; n++) Vfin[((size_t)chunk * 64 + tid) * 8 + n] = s[n];
    }
}

// ---------------------------------------------------------------------------
// Kernel B (fused compose+expand): threads 0..15 compose this chunk's start
// state, then all 256 threads fine-expand, writing f16-pair planes
// hTu[8][NROWS] (plane p = features 2p,2p+1 of its c-half).
// ---------------------------------------------------------------------------
__global__ __launch_bounds__(256) void hippo_expand_kernel(
    const float* __restrict__ x_seq,
    const float* __restrict__ Psub,
    const float* __restrict__ Vsub,
    const float* __restrict__ Pfin,
    const float* __restrict__ Vfin,
    unsigned int* __restrict__ hTu)      // [8][NROWS] f16-pairs
{
    __shared__ float sLDS[16][8];
    int tid = threadIdx.x;
    int sub = tid & 15;
    int c = (tid >> 4) & 1;
    int blo = tid >> 5;                  // 0..7
    int bhi = blockIdx.x & 3;            // 0..3
    int chunk = blockIdx.x >> 2;         // 0..63
    int b = bhi * 8 + blo;
    int seq = b * 2 + c;

    if (tid < 16) {
        int useq = (bhi * 8 + (tid >> 1)) * 2 + (tid & 1);
        float s[8];
        #pragma unroll
        for (int n = 0; n < 8; n++) s[n] = 0.0f;
        for (int ck = 0; ck < 64; ck++) {
            if (ck >= chunk) break;
            float ns[8];
            #pragma unroll
            for (int n = 0; n < 8; n++) {
                float acc = Vfin[((size_t)ck * 64 + useq) * 8 + n];
                #pragma unroll
                for (int m = 0; m < 8; m++)
                    acc = fmaf(Pfin[((size_t)ck * 8 + n) * 8 + m], s[m], acc);
                ns[n] = acc;
            }
            #pragma unroll
            for (int n = 0; n < 8; n++) s[n] = ns[n];
        }
        #pragma unroll
        for (int n = 0; n < 8; n++) sLDS[tid][n] = s[n];
    }
    __syncthreads();

    float s0v[8];
    {
        int u = blo * 2 + c;
        #pragma unroll
        for (int n = 0; n < 8; n++) s0v[n] = sLDS[u][n];
    }

    const float* Pp = &Psub[((size_t)chunk * NSUB + sub) * 64];
    const float* Vp = &Vsub[(((size_t)chunk * NSUB + sub) * 64 + seq) * 8];

    float s[8];
    #pragma unroll
    for (int n = 0; n < 8; n++) {
        float acc = Vp[n];
        #pragma unroll
        for (int m = 0; m < 8; m++)
            acc = fmaf(Pp[n * 8 + m], s0v[m], acc);
        s[n] = acc;
    }

    int t0 = chunk * CLEN + sub * SUBL;
    size_t rowbase = (size_t)b * TLEN;

    unsigned int dw[4][8];               // [pair k][step t]
    #pragma unroll
    for (int i = 0; i < SUBL; i++) {
        int t = t0 + i;
        float tf = (float)(t + 1);
        float inv_t = 1.0f / tf;
        float x = x_seq[(rowbase + t) * 2 + c];
        hippo_step(s, inv_t, x * inv_t);
        #pragma unroll
        for (int k = 0; k < 4; k++)
            dw[k][i] = pkh(s[2 * k], s[2 * k + 1]);
    }
    #pragma unroll
    for (int k = 0; k < 4; k++) {
        int plane = c * 4 + k;
        uint4* dst = (uint4*)&hTu[(size_t)plane * NROWS + rowbase + t0];
        dst[0] = make_uint4(dw[k][0], dw[k][1], dw[k][2], dw[k][3]);
        dst[1] = make_uint4(dw[k][4], dw[k][5], dw[k][6], dw[k][7]);
    }
}

// ---------------------------------------------------------------------------
// KAN helpers
// ---------------------------------------------------------------------------
__device__ __forceinline__ void bspline4(float x, float& B0, float& B1,
                                         float& B2, float& B3, int& m)
{
    float tt = fmaf(x, 5.0f, 8.0f);        // (x + 1.6) * 5
    float fm = floorf(tt);
    float u = tt - fm;
    bool valid = (fm >= 0.0f) && (fm <= 15.0f);
    float u2 = u * u, u3 = u2 * u;
    float um = 1.0f - u;
    B0 = um * um * um * (1.0f / 6.0f);
    B3 = u3 * (1.0f / 6.0f);
    B1 = fmaf(3.0f, u3, fmaf(-6.0f, u2, 4.0f)) * (1.0f / 6.0f);
    B2 = fmaf(-3.0f, u3, fmaf(3.0f, u2, fmaf(3.0f, u, 1.0f))) * (1.0f / 6.0f);
    float msk = valid ? 1.0f : 0.0f;
    B0 *= msk; B1 *= msk; B2 *= msk; B3 *= msk;
    m = valid ? (int)fm : 0;
}

__device__ __forceinline__ float silu(float x) {
    return x / (1.0f + __expf(-x));
}

__device__ __forceinline__ int poffm(int m) {
    return (m & 1) ? (10 + ((m - 1) >> 1)) : (m >> 1);
}

// TWO ROWS PER THREAD: identical instruction stream, two independent
// dependence chains per slot (latency-bound fix; round-8 analysis showed
// 4x issue headroom). Rolled pair-loops, f16-pair activations, LDS holds
// spline weights only (38912 B). No launch_bounds min-waves (spill lesson).
__global__ __launch_bounds__(256) void kan_kernel(
    const unsigned int* __restrict__ hTu,    // [8][NROWS] f16 pairs
    unsigned int* __restrict__ out1Tu,       // [16][NROWS] f16 pairs
    const float* __restrict__ wb1, const float* __restrict__ ws1,
    const float* __restrict__ wb2, const float* __restrict__ ws2,
    const float* __restrict__ wb3, const float* __restrict__ ws3,
    float* __restrict__ out)
{
    __shared__ unsigned int wldsU[9728];     // 38912 B
    int tid = threadIdx.x;
    int row0 = blockIdx.x * 512 + tid;
    int row1 = row0 + 256;

    // ---- stage phase 1 (affine)
    {
        int i = tid >> 4, q = tid & 15;
        #pragma unroll
        for (int oo = 0; oo < 2; oo++) {
            int o = q + oo * 16;
            const float* src = ws1 + o * 208 + i * 13;
            int dst = i * 608 + o * 19;
            #pragma unroll
            for (int p = 0; p < 19; p++) {
                int j0 = (p < 10) ? (2 * p) : (2 * (p - 10) + 1);
                float lo = (j0 >= 3 && j0 <= 15) ? src[j0 - 3] : 0.0f;
                float hi = (j0 + 1 >= 3 && j0 + 1 <= 15) ? src[j0 - 2] : 0.0f;
                wldsU[dst + p] = pkh(lo, hi);
            }
        }
    }
    __syncthreads();

    // ---- layer 1: 16 -> 32, two rows
    float a1A[32], a1B[32];
    #pragma unroll
    for (int o = 0; o < 32; o++) { a1A[o] = 0.0f; a1B[o] = 0.0f; }

    unsigned int c0 = hTu[row0], c1 = hTu[row1];
    unsigned int n0 = hTu[(size_t)NROWS + row0], n1 = hTu[(size_t)NROWS + row1];
    #pragma unroll 1
    for (int pi = 0; pi < 8; pi++) {
        unsigned int f0 = hTu[(size_t)((pi + 2) & 7) * NROWS + row0];
        unsigned int f1 = hTu[(size_t)((pi + 2) & 7) * NROWS + row1];
        h2 xpA = u2h(c0), xpB = u2h(c1);
        #pragma unroll
        for (int par = 0; par < 2; par++) {
            int i = 2 * pi + par;
            float xA = par ? (float)xpA.y : (float)xpA.x;
            float xB = par ? (float)xpB.y : (float)xpB.x;
            float sxA = silu(xA), sxB = silu(xB);
            float A0, A1, A2, A3; int mA;
            bspline4(xA, A0, A1, A2, A3, mA);
            float Bq0, Bq1, Bq2, Bq3; int mB;
            bspline4(xB, Bq0, Bq1, Bq2, Bq3, mB);
            h2 A01 = u2h(pkh(A0, A1)), A23 = u2h(pkh(A2, A3));
            h2 B01 = u2h(pkh(Bq0, Bq1)), B23 = u2h(pkh(Bq2, Bq3));
            int baseA = i * 608 + poffm(mA);
            int baseB = i * 608 + poffm(mB);
            const float* wbrow = wb1 + i;       // wb1[o*16+i]
            #pragma unroll
            for (int o = 0; o < 32; o++) {
                unsigned int dAa = wldsU[baseA + o * 19];
                unsigned int dAb = wldsU[baseA + o * 19 + 1];
                unsigned int dBa = wldsU[baseB + o * 19];
                unsigned int dBb = wldsU[baseB + o * 19 + 1];
                float wbv = wbrow[o * 16];
                float aA = a1A[o];
                aA = dot2f(A01, u2h(dAa), aA);
                aA = dot2f(A23, u2h(dAb), aA);
                aA = fmaf(sxA, wbv, aA);
                a1A[o] = aA;
                float aB = a1B[o];
                aB = dot2f(B01, u2h(dBa), aB);
                aB = dot2f(B23, u2h(dBb), aB);
                aB = fmaf(sxB, wbv, aB);
                a1B[o] = aB;
            }
        }
        c0 = n0; n0 = f0;
        c1 = n1; n1 = f1;
    }
    #pragma unroll
    for (int op = 0; op < 16; op++) {
        out1Tu[(size_t)op * NROWS + row0] = pkh(a1A[2 * op], a1A[2 * op + 1]);
        out1Tu[(size_t)op * NROWS + row1] = pkh(a1B[2 * op], a1B[2 * op + 1]);
    }
    __syncthreads();

    // ---- stage phase 2 (affine)
    {
        int i = tid >> 3, q = tid & 7;
        #pragma unroll
        for (int oo = 0; oo < 2; oo++) {
            int o = q + oo * 8;
            const float* src = ws2 + o * 416 + i * 13;
            int dst = i * 304 + o * 19;
            #pragma unroll
            for (int p = 0; p < 19; p++) {
                int j0 = (p < 10) ? (2 * p) : (2 * (p - 10) + 1);
                float lo = (j0 >= 3 && j0 <= 15) ? src[j0 - 3] : 0.0f;
                float hi = (j0 + 1 >= 3 && j0 + 1 <= 15) ? src[j0 - 2] : 0.0f;
                wldsU[dst + p] = pkh(lo, hi);
            }
        }
    }
    __syncthreads();

    // ---- layer 2: 32 -> 16, two rows
    float a2A[16], a2B[16];
    #pragma unroll
    for (int o = 0; o < 16; o++) { a2A[o] = 0.0f; a2B[o] = 0.0f; }

    c0 = out1Tu[row0]; c1 = out1Tu[row1];
    n0 = out1Tu[(size_t)NROWS + row0]; n1 = out1Tu[(size_t)NROWS + row1];
    #pragma unroll 1
    for (int pi = 0; pi < 16; pi++) {
        unsigned int f0 = out1Tu[(size_t)((pi + 2) & 15) * NROWS + row0];
        unsigned int f1 = out1Tu[(size_t)((pi + 2) & 15) * NROWS + row1];
        h2 ypA = u2h(c0), ypB = u2h(c1);
        #pragma unroll
        for (int par = 0; par < 2; par++) {
            int i = 2 * pi + par;
            float yA = par ? (float)ypA.y : (float)ypA.x;
            float yB = par ? (float)ypB.y : (float)ypB.x;
            float sxA = silu(yA), sxB = silu(yB);
            float A0, A1, A2, A3; int mA;
            bspline4(yA, A0, A1, A2, A3, mA);
            float Bq0, Bq1, Bq2, Bq3; int mB;
            bspline4(yB, Bq0, Bq1, Bq2, Bq3, mB);
            h2 A01 = u2h(pkh(A0, A1)), A23 = u2h(pkh(A2, A3));
            h2 B01 = u2h(pkh(Bq0, Bq1)), B23 = u2h(pkh(Bq2, Bq3));
            int baseA = i * 304 + poffm(mA);
            int baseB = i * 304 + poffm(mB);
            const float* wbrow = wb2 + i;       // wb2[o*32+i]
            #pragma unroll
            for (int o = 0; o < 16; o++) {
                unsigned int dAa = wldsU[baseA + o * 19];
                unsigned int dAb = wldsU[baseA + o * 19 + 1];
                unsigned int dBa = wldsU[baseB + o * 19];
                unsigned int dBb = wldsU[baseB + o * 19 + 1];
                float wbv = wbrow[o * 32];
                float aA = a2A[o];
                aA = dot2f(A01, u2h(dAa), aA);
                aA = dot2f(A23, u2h(dAb), aA);
                aA = fmaf(sxA, wbv, aA);
                a2A[o] = aA;
                float aB = a2B[o];
                aB = dot2f(B01, u2h(dBa), aB);
                aB = dot2f(B23, u2h(dBb), aB);
                aB = fmaf(sxB, wbv, aB);
                a2B[o] = aB;
            }
        }
        c0 = n0; n0 = f0;
        c1 = n1; n1 = f1;
    }

    // ---- layer 3: 16 -> 1, both rows, fp32 weights from global
    float acc3A = 0.0f, acc3B = 0.0f;
    #pragma unroll
    for (int i = 0; i < 16; i++) {
        const float* w3 = &ws3[i * 13];
        float wbv = wb3[i];
        {
            float xv = a2A[i];
            float sx = silu(xv);
            float B0, B1, B2, B3; int m;
            bspline4(xv, B0, B1, B2, B3, m);
            acc3A = fmaf(sx, wbv, acc3A);
            int j0 = m - 3;
            float w0v = (j0 >= 0)              ? w3[j0]     : 0.0f;
            float w1v = (j0 >= -1 && j0 <= 11) ? w3[j0 + 1] : 0.0f;
            float w2v = (j0 >= -2 && j0 <= 10) ? w3[j0 + 2] : 0.0f;
            float w3v = (j0 <= 9)              ? w3[j0 + 3] : 0.0f;
            acc3A = fmaf(B0, w0v, acc3A);
            acc3A = fmaf(B1, w1v, acc3A);
            acc3A = fmaf(B2, w2v, acc3A);
            acc3A = fmaf(B3, w3v, acc3A);
        }
        {
            float xv = a2B[i];
            float sx = silu(xv);
            float B0, B1, B2, B3; int m;
            bspline4(xv, B0, B1, B2, B3, m);
            acc3B = fmaf(sx, wbv, acc3B);
            int j0 = m - 3;
            float w0v = (j0 >= 0)              ? w3[j0]     : 0.0f;
            float w1v = (j0 >= -1 && j0 <= 11) ? w3[j0 + 1] : 0.0f;
            float w2v = (j0 >= -2 && j0 <= 10) ? w3[j0 + 2] : 0.0f;
            float w3v = (j0 <= 9)              ? w3[j0 + 3] : 0.0f;
            acc3B = fmaf(B0, w0v, acc3B);
            acc3B = fmaf(B1, w1v, acc3B);
            acc3B = fmaf(B2, w2v, acc3B);
            acc3B = fmaf(B3, w3v, acc3B);
        }
    }
    out[row0] = acc3A;
    out[row1] = acc3B;
}

// ---------------------------------------------------------------------------
extern "C" void kernel_launch(void* const* d_in, const int* in_sizes, int n_in,
                              void* d_out, int out_size, void* d_ws, size_t ws_size,
                              hipStream_t stream) {
    const float* x_seq = (const float*)d_in[0];
    const float* wb1   = (const float*)d_in[1];
    const float* ws1   = (const float*)d_in[2];
    const float* wb2   = (const float*)d_in[3];
    const float* ws2   = (const float*)d_in[4];
    const float* wb3   = (const float*)d_in[5];
    const float* ws3   = (const float*)d_in[6];

    float* ws   = (float*)d_ws;
    float* Psub = ws;                   // 64*16*64        =   65536
    float* Vsub = ws + 65536;           // 64*16*64*8      =  524288
    float* Pfin = ws + 589824;          // 64*64           =    4096
    float* Vfin = ws + 593920;          // 64*64*8         =   32768
    unsigned int* hTu    = (unsigned int*)(ws + 626688);   // 8*262144  dw
    unsigned int* out1Tu = (unsigned int*)(ws + 2723840);  // 16*262144 dw
    float* out  = (float*)d_out;

    hipLaunchKernelGGL(hippo_chunk_kernel,   dim3(NCH), dim3(128), 0, stream,
                       x_seq, Psub, Vsub, Pfin, Vfin);
    hipLaunchKernelGGL(hippo_expand_kernel,  dim3(NCH * 4), dim3(256), 0, stream,
                       x_seq, Psub, Vsub, Pfin, Vfin, hTu);
    hipLaunchKernelGGL(kan_kernel, dim3(NROWS / 512), dim3(256), 0, stream,
                       hTu, out1Tu, wb1, ws1, wb2, ws2, wb3, ws3, out);
}

// Round 10
// 131.973 us; speedup vs baseline: 1.1776x; 1.1776x over previous
//
#include <hip/hip_runtime.h>
#include <math.h>

#define BATCH 32
#define TLEN 8192
#define NCH 64           // chunks
#define CLEN 128         // steps per chunk
#define SUBL 8           // steps per sub-chunk
#define NSUB 16          // sub-chunks per chunk
#define NROWS (BATCH*TLEN)   // 262144 rows

typedef _Float16 h2 __attribute__((ext_vector_type(2)));
union HU { unsigned int u; h2 h; };
__device__ __forceinline__ h2 u2h(unsigned int x) { HU t; t.u = x; return t.h; }
__device__ __forceinline__ unsigned int pkh(float a, float b) {
    HU t; t.h = h2{(_Float16)a, (_Float16)b}; return t.u;
}

#if __has_builtin(__builtin_amdgcn_fdot2)
__device__ __forceinline__ float dot2f(h2 a, h2 b, float c) {
    return __builtin_amdgcn_fdot2(a, b, c, false);
}
#else
__device__ __forceinline__ float dot2f(h2 a, h2 b, float c) {
    return fmaf((float)a.x, (float)b.x, fmaf((float)a.y, (float)b.y, c));
}
#endif

// ---------------------------------------------------------------------------
// HiPPO step, tree-form prefix: s <- (I - A/t) s + (x/t) * r
// ---------------------------------------------------------------------------
__device__ __forceinline__ void hippo_step(float s[8], float inv_t, float xb) {
    const float R[8] = {1.0f, 1.7320508075688772f, 2.23606797749979f,
                        2.6457513110645907f, 3.0f, 3.3166247903554f,
                        3.605551275463989f, 3.872983346207417f};
    float q0 = R[0]*s[0], q1 = R[1]*s[1], q2 = R[2]*s[2], q3 = R[3]*s[3];
    float q4 = R[4]*s[4], q5 = R[5]*s[5], q6 = R[6]*s[6];
    float t01 = q0+q1, t23 = q2+q3, t45 = q4+q5;
    float p1 = q0, p2 = t01, p3 = t01+q2, p4 = t01+t23;
    float p5 = p4+q4, p6 = p4+t45, p7 = p6+q6;
    float p[8] = {0.0f, p1, p2, p3, p4, p5, p6, p7};
    #pragma unroll
    for (int n = 0; n < 8; n++) {
        float as = fmaf(R[n], p[n], (float)(n + 1) * s[n]);
        s[n] = fmaf(-inv_t, as, fmaf(xb, R[n], s[n]));
    }
}

// ---------------------------------------------------------------------------
// Kernel A: per-chunk runs with 8-wide batched + double-buffered x loads.
// ---------------------------------------------------------------------------
__global__ void hippo_chunk_kernel(const float* __restrict__ x_seq,
                                   float* __restrict__ Psub,  // [NCH][NSUB][8][8]
                                   float* __restrict__ Vsub,  // [NCH][NSUB][64][8]
                                   float* __restrict__ Pfin,  // [NCH][8][8]
                                   float* __restrict__ Vfin)  // [NCH][64][8]
{
    int chunk = blockIdx.x;
    int tid = threadIdx.x;
    if (tid >= 72) return;
    bool isP = tid >= 64;
    int col = tid - 64;
    int b = tid >> 1, c = tid & 1;

    float s[8];
    #pragma unroll
    for (int n = 0; n < 8; n++) s[n] = (isP && n == col) ? 1.0f : 0.0f;

    int t0c = chunk * CLEN;
    size_t xbase = ((size_t)b * TLEN + t0c) * 2 + c;

    float xl[8];
    #pragma unroll
    for (int k = 0; k < 8; k++)
        xl[k] = isP ? 0.0f : x_seq[xbase + 2 * k];

    #pragma unroll 1
    for (int ii = 0; ii < CLEN; ii += 8) {
        int sub = ii >> 3;
        if (isP) {
            #pragma unroll
            for (int n = 0; n < 8; n++)
                Psub[(((size_t)chunk * NSUB + sub) * 8 + n) * 8 + col] = s[n];
        } else {
            #pragma unroll
            for (int n = 0; n < 8; n++)
                Vsub[(((size_t)chunk * NSUB + sub) * 64 + tid) * 8 + n] = s[n];
        }
        float xn8[8];
        bool more = (ii + 8 < CLEN) && !isP;
        #pragma unroll
        for (int k = 0; k < 8; k++)
            xn8[k] = more ? x_seq[xbase + 2 * (ii + 8 + k)] : 0.0f;

        #pragma unroll
        for (int k = 0; k < 8; k++) {
            float tf = (float)(t0c + ii + k + 1);
            float inv_t = 1.0f / tf;
            hippo_step(s, inv_t, xl[k] * inv_t);
        }
        #pragma unroll
        for (int k = 0; k < 8; k++) xl[k] = xn8[k];
    }
    if (isP) {
        #pragma unroll
        for (int n = 0; n < 8; n++) Pfin[((size_t)chunk * 8 + n) * 8 + col] = s[n];
    } else {
        #pragma unroll
        for (int n = 0; n < 8; n++) Vfin[((size_t)chunk * 64 + tid) * 8 + n] = s[n];
    }
}

// ---------------------------------------------------------------------------
// Kernel B (fused compose+expand): threads 0..15 compose this chunk's start
// state, then all 256 threads fine-expand, writing f16-pair planes
// hTu[8][NROWS].
// ---------------------------------------------------------------------------
__global__ __launch_bounds__(256) void hippo_expand_kernel(
    const float* __restrict__ x_seq,
    const float* __restrict__ Psub,
    const float* __restrict__ Vsub,
    const float* __restrict__ Pfin,
    const float* __restrict__ Vfin,
    unsigned int* __restrict__ hTu)      // [8][NROWS] f16-pairs
{
    __shared__ float sLDS[16][8];
    int tid = threadIdx.x;
    int sub = tid & 15;
    int c = (tid >> 4) & 1;
    int blo = tid >> 5;                  // 0..7
    int bhi = blockIdx.x & 3;            // 0..3
    int chunk = blockIdx.x >> 2;         // 0..63
    int b = bhi * 8 + blo;
    int seq = b * 2 + c;

    if (tid < 16) {
        int useq = (bhi * 8 + (tid >> 1)) * 2 + (tid & 1);
        float s[8];
        #pragma unroll
        for (int n = 0; n < 8; n++) s[n] = 0.0f;
        for (int ck = 0; ck < 64; ck++) {
            if (ck >= chunk) break;
            float ns[8];
            #pragma unroll
            for (int n = 0; n < 8; n++) {
                float acc = Vfin[((size_t)ck * 64 + useq) * 8 + n];
                #pragma unroll
                for (int m = 0; m < 8; m++)
                    acc = fmaf(Pfin[((size_t)ck * 8 + n) * 8 + m], s[m], acc);
                ns[n] = acc;
            }
            #pragma unroll
            for (int n = 0; n < 8; n++) s[n] = ns[n];
        }
        #pragma unroll
        for (int n = 0; n < 8; n++) sLDS[tid][n] = s[n];
    }
    __syncthreads();

    float s0v[8];
    {
        int u = blo * 2 + c;
        #pragma unroll
        for (int n = 0; n < 8; n++) s0v[n] = sLDS[u][n];
    }

    const float* Pp = &Psub[((size_t)chunk * NSUB + sub) * 64];
    const float* Vp = &Vsub[(((size_t)chunk * NSUB + sub) * 64 + seq) * 8];

    float s[8];
    #pragma unroll
    for (int n = 0; n < 8; n++) {
        float acc = Vp[n];
        #pragma unroll
        for (int m = 0; m < 8; m++)
            acc = fmaf(Pp[n * 8 + m], s0v[m], acc);
        s[n] = acc;
    }

    int t0 = chunk * CLEN + sub * SUBL;
    size_t rowbase = (size_t)b * TLEN;

    unsigned int dw[4][8];
    #pragma unroll
    for (int i = 0; i < SUBL; i++) {
        int t = t0 + i;
        float tf = (float)(t + 1);
        float inv_t = 1.0f / tf;
        float x = x_seq[(rowbase + t) * 2 + c];
        hippo_step(s, inv_t, x * inv_t);
        #pragma unroll
        for (int k = 0; k < 4; k++)
            dw[k][i] = pkh(s[2 * k], s[2 * k + 1]);
    }
    #pragma unroll
    for (int k = 0; k < 4; k++) {
        int plane = c * 4 + k;
        uint4* dst = (uint4*)&hTu[(size_t)plane * NROWS + rowbase + t0];
        dst[0] = make_uint4(dw[k][0], dw[k][1], dw[k][2], dw[k][3]);
        dst[1] = make_uint4(dw[k][4], dw[k][5], dw[k][6], dw[k][7]);
    }
}

// ---------------------------------------------------------------------------
// KAN helpers
// ---------------------------------------------------------------------------
__device__ __forceinline__ void bspline4(float x, float& B0, float& B1,
                                         float& B2, float& B3, int& m)
{
    float tt = fmaf(x, 5.0f, 8.0f);        // (x + 1.6) * 5
    float fm = floorf(tt);
    float u = tt - fm;
    bool valid = (fm >= 0.0f) && (fm <= 15.0f);
    float u2 = u * u, u3 = u2 * u;
    float um = 1.0f - u;
    B0 = um * um * um * (1.0f / 6.0f);
    B3 = u3 * (1.0f / 6.0f);
    B1 = fmaf(3.0f, u3, fmaf(-6.0f, u2, 4.0f)) * (1.0f / 6.0f);
    B2 = fmaf(-3.0f, u3, fmaf(3.0f, u2, fmaf(3.0f, u, 1.0f))) * (1.0f / 6.0f);
    float msk = valid ? 1.0f : 0.0f;
    B0 *= msk; B1 *= msk; B2 *= msk; B3 *= msk;
    m = valid ? (int)fm : 0;
}

__device__ __forceinline__ float silu(float x) {
    return x / (1.0f + __expf(-x));
}

// [i][m][o] SLOT TABLE: each 8B slot = all 4 f16 taps of edge (i,o) at
// interval m (the o-loop's lane-invariant). One ds_read_b128 covers TWO o's
// -> 4x fewer LDS instructions (round-8 bottleneck: LDS instr issue ~79us).
// Even rotation phys=(o+2m)&31 spreads distinct-m lanes across bank groups;
// equal-m lanes read the SAME address (broadcast, free).
// LDS 65536 B -> 2 blocks/CU. One row per thread (round-9: TLP > ILP).
__global__ __launch_bounds__(256) void kan_kernel(
    const unsigned int* __restrict__ hTu,    // [8][NROWS] f16 pairs
    unsigned int* __restrict__ out1Tu,       // [16][NROWS] f16 pairs
    const float* __restrict__ wb1, const float* __restrict__ ws1,
    const float* __restrict__ wb2, const float* __restrict__ ws2,
    const float* __restrict__ wb3, const float* __restrict__ ws3,
    float* __restrict__ out)
{
    // phase1: rows (i*16+m) of 256B, 32 slots; phase2: rows of 128B, 16 slots
    __shared__ uint2 wslot[8192];            // 65536 B, 8B slots
    int tid = threadIdx.x;
    int row = blockIdx.x * 256 + tid;

    // ---- stage phase 1: 512 edges (i<16,o<32), 2 per thread
    #pragma unroll
    for (int e = 0; e < 2; e++) {
        int edge = tid + e * 256;
        int i = edge >> 5, o = edge & 31;
        const float* src = ws1 + o * 208 + i * 13;
        unsigned short wp[19];
        #pragma unroll
        for (int j = 0; j < 19; j++) {
            float v = (j >= 3 && j <= 15) ? src[j - 3] : 0.0f;
            HU t; t.h = h2{(_Float16)v, (_Float16)0.0f};
            wp[j] = (unsigned short)(t.u & 0xFFFFu);
        }
        #pragma unroll
        for (int m = 0; m < 16; m++) {
            unsigned int d0 = (unsigned int)wp[m]     | ((unsigned int)wp[m + 1] << 16);
            unsigned int d1 = (unsigned int)wp[m + 2] | ((unsigned int)wp[m + 3] << 16);
            int p = (o + 2 * m) & 31;
            wslot[(i * 16 + m) * 32 + p] = make_uint2(d0, d1);
        }
    }
    __syncthreads();

    // ---- layer 1: 16 -> 32 (rolled over 8 input pairs)
    float acc1[32];
    #pragma unroll
    for (int o = 0; o < 32; o++) acc1[o] = 0.0f;

    unsigned int cur = hTu[row];
    unsigned int nxt = hTu[(size_t)NROWS + row];
    #pragma unroll 1
    for (int pi = 0; pi < 8; pi++) {
        unsigned int fut = hTu[(size_t)((pi + 2) & 7) * NROWS + row];
        h2 xp = u2h(cur);
        #pragma unroll
        for (int par = 0; par < 2; par++) {
            int i = 2 * pi + par;
            float xv = (par == 0) ? (float)xp.x : (float)xp.y;
            float sx = silu(xv);
            float B0, B1, B2, B3; int m;
            bspline4(xv, B0, B1, B2, B3, m);
            h2 B01 = u2h(pkh(B0, B1));
            h2 B23 = u2h(pkh(B2, B3));
            const char* rowp = (const char*)wslot + (i * 4096 + m * 256);
            const float* wbrow = wb1 + i;       // wb1[o*16+i], lane-uniform
            #pragma unroll
            for (int k = 0; k < 16; k++) {
                uint4 d = *(const uint4*)(rowp + (((k + m) & 15) << 4));
                float aE = acc1[2 * k];
                aE = dot2f(B01, u2h(d.x), aE);
                aE = dot2f(B23, u2h(d.y), aE);
                aE = fmaf(sx, wbrow[(2 * k) * 16], aE);
                acc1[2 * k] = aE;
                float aO = acc1[2 * k + 1];
                aO = dot2f(B01, u2h(d.z), aO);
                aO = dot2f(B23, u2h(d.w), aO);
                aO = fmaf(sx, wbrow[(2 * k + 1) * 16], aO);
                acc1[2 * k + 1] = aO;
            }
        }
        cur = nxt; nxt = fut;
    }
    #pragma unroll
    for (int op = 0; op < 16; op++)
        out1Tu[(size_t)op * NROWS + row] = pkh(acc1[2 * op], acc1[2 * op + 1]);

    __syncthreads();   // all waves done reading phase-1 table

    // ---- stage phase 2: 512 edges (i<32,o<16), 2 per thread
    #pragma unroll
    for (int e = 0; e < 2; e++) {
        int edge = tid + e * 256;
        int i = edge >> 4, o = edge & 15;
        const float* src = ws2 + o * 416 + i * 13;
        unsigned short wp[19];
        #pragma unroll
        for (int j = 0; j < 19; j++) {
            float v = (j >= 3 && j <= 15) ? src[j - 3] : 0.0f;
            HU t; t.h = h2{(_Float16)v, (_Float16)0.0f};
            wp[j] = (unsigned short)(t.u & 0xFFFFu);
        }
        #pragma unroll
        for (int m = 0; m < 16; m++) {
            unsigned int d0 = (unsigned int)wp[m]     | ((unsigned int)wp[m + 1] << 16);
            unsigned int d1 = (unsigned int)wp[m + 2] | ((unsigned int)wp[m + 3] << 16);
            int p = (o + 2 * m) & 15;
            wslot[(i * 16 + m) * 16 + p] = make_uint2(d0, d1);
        }
    }
    __syncthreads();

    // ---- layer 2: 32 -> 16 (rolled over 16 input pairs)
    float acc2[16];
    #pragma unroll
    for (int o = 0; o < 16; o++) acc2[o] = 0.0f;

    cur = out1Tu[row];
    nxt = out1Tu[(size_t)NROWS + row];
    #pragma unroll 1
    for (int pi = 0; pi < 16; pi++) {
        unsigned int fut = out1Tu[(size_t)((pi + 2) & 15) * NROWS + row];
        h2 yp = u2h(cur);
        #pragma unroll
        for (int par = 0; par < 2; par++) {
            int i = 2 * pi + par;
            float yv = (par == 0) ? (float)yp.x : (float)yp.y;
            float sx = silu(yv);
            float B0, B1, B2, B3; int m;
            bspline4(yv, B0, B1, B2, B3, m);
            h2 B01 = u2h(pkh(B0, B1));
            h2 B23 = u2h(pkh(B2, B3));
            const char* rowp = (const char*)wslot + (i * 2048 + m * 128);
            const float* wbrow = wb2 + i;       // wb2[o*32+i], lane-uniform
            #pragma unroll
            for (int k = 0; k < 8; k++) {
                uint4 d = *(const uint4*)(rowp + (((k + m) & 7) << 4));
                float aE = acc2[2 * k];
                aE = dot2f(B01, u2h(d.x), aE);
                aE = dot2f(B23, u2h(d.y), aE);
                aE = fmaf(sx, wbrow[(2 * k) * 32], aE);
                acc2[2 * k] = aE;
                float aO = acc2[2 * k + 1];
                aO = dot2f(B01, u2h(d.z), aO);
                aO = dot2f(B23, u2h(d.w), aO);
                aO = fmaf(sx, wbrow[(2 * k + 1) * 32], aO);
                acc2[2 * k + 1] = aO;
            }
        }
        cur = nxt; nxt = fut;
    }

    // ---- layer 3: 16 -> 1, fully unrolled, fp32 weights from global
    float acc3 = 0.0f;
    #pragma unroll
    for (int i = 0; i < 16; i++) {
        float xv = acc2[i];
        float sx = silu(xv);
        float B0, B1, B2, B3; int m;
        bspline4(xv, B0, B1, B2, B3, m);
        acc3 = fmaf(sx, wb3[i], acc3);
        const float* w3 = &ws3[i * 13];
        int j0 = m - 3;
        float w0v = (j0 >= 0)              ? w3[j0]     : 0.0f;
        float w1v = (j0 >= -1 && j0 <= 11) ? w3[j0 + 1] : 0.0f;
        float w2v = (j0 >= -2 && j0 <= 10) ? w3[j0 + 2] : 0.0f;
        float w3v = (j0 <= 9)              ? w3[j0 + 3] : 0.0f;
        acc3 = fmaf(B0, w0v, acc3);
        acc3 = fmaf(B1, w1v, acc3);
        acc3 = fmaf(B2, w2v, acc3);
        acc3 = fmaf(B3, w3v, acc3);
    }
    out[row] = acc3;
}

// ---------------------------------------------------------------------------
extern "C" void kernel_launch(void* const* d_in, const int* in_sizes, int n_in,
                              void* d_out, int out_size, void* d_ws, size_t ws_size,
                              hipStream_t stream) {
    const float* x_seq = (const float*)d_in[0];
    const float* wb1   = (const float*)d_in[1];
    const float* ws1   = (const float*)d_in[2];
    const float* wb2   = (const float*)d_in[3];
    const float* ws2   = (const float*)d_in[4];
    const float* wb3   = (const float*)d_in[5];
    const float* ws3   = (const float*)d_in[6];

    float* ws   = (float*)d_ws;
    float* Psub = ws;                   // 64*16*64        =   65536
    float* Vsub = ws + 65536;           // 64*16*64*8      =  524288
    float* Pfin = ws + 589824;          // 64*64           =    4096
    float* Vfin = ws + 593920;          // 64*64*8         =   32768
    unsigned int* hTu    = (unsigned int*)(ws + 626688);   // 8*262144  dw
    unsigned int* out1Tu = (unsigned int*)(ws + 2723840);  // 16*262144 dw
    float* out  = (float*)d_out;

    hipLaunchKernelGGL(hippo_chunk_kernel,   dim3(NCH), dim3(128), 0, stream,
                       x_seq, Psub, Vsub, Pfin, Vfin);
    hipLaunchKernelGGL(hippo_expand_kernel,  dim3(NCH * 4), dim3(256), 0, stream,
                       x_seq, Psub, Vsub, Pfin, Vfin, hTu);
    hipLaunchKernelGGL(kan_kernel, dim3(NROWS / 256), dim3(256), 0, stream,
                       hTu, out1Tu, wb1, ws1, wb2, ws2, wb3, ws3, out);
}